// Round 12
// baseline (194.578 us; speedup 1.0000x reference)
//
#include <hip/hip_runtime.h>

#define BB 64
#define SS 512
#define HH 768
#define HH4 (HH / 4)      // 192 float4 per row
#define NBD 5
#define NC 9
#define NR 4096
#define NB_BD 2048

// ---------------------------------------------------------------------------
// Kernel 1: boundary loss with wave-uniform seg-skip. Each wave handles 4
// tokens (gw + 8192*i). seg[token] is wave-uniform -> readfirstlane + scalar
// branch skips the ENTIRE row read + dot + butterfly + softmax for seg==0
// (~50% of tokens). Ws fragment register-resident. Launched FIRST so the
// seg==1 half of word_repr lands in L3 for the region kernel.
// ---------------------------------------------------------------------------
__global__ __launch_bounds__(256) void bd_kernel(
    const float* __restrict__ wr, const float* __restrict__ Ws,
    const float* __restrict__ bs, const int* __restrict__ tgt,
    const int* __restrict__ seg, float2* __restrict__ out_part)
{
    const int wid  = threadIdx.x >> 6;
    const int lane = threadIdx.x & 63;
    const int gw   = blockIdx.x * 4 + wid;   // 0..8191

    // Ws fragment: h = 4*lane + 256*j + e, loaded as contiguous float4
    float wreg[3][4][NBD];
    #pragma unroll
    for (int j = 0; j < 3; ++j) {
        const float4* wp = (const float4*)(Ws + (4 * lane + 256 * j) * NBD);
        #pragma unroll
        for (int p = 0; p < 5; ++p) {
            const float4 f = wp[p];
            const float vv[4] = {f.x, f.y, f.z, f.w};
            #pragma unroll
            for (int q = 0; q < 4; ++q) {
                const int flat = 4 * p + q;            // 0..19
                wreg[j][flat / NBD][flat % NBD] = vv[q];
            }
        }
    }
    const float b0 = bs[0], b1 = bs[1], b2 = bs[2], b3 = bs[3], b4 = bs[4];

    float nll_sum = 0.f, msk_sum = 0.f;

    #pragma unroll
    for (int i = 0; i < 4; ++i) {
        const int token = gw + 8192 * i;
        // wave-uniform mask -> scalar branch; skips load+compute entirely
        const int m_u = __builtin_amdgcn_readfirstlane(seg[token]);
        if (m_u != 0) {
            const float4* row4 = (const float4*)(wr + (size_t)token * HH);

            float4 v[3];
            #pragma unroll
            for (int j = 0; j < 3; ++j) v[j] = row4[lane + 64 * j];

            float dot[NBD] = {0.f, 0.f, 0.f, 0.f, 0.f};
            #pragma unroll
            for (int j = 0; j < 3; ++j) {
                const float x[4] = {v[j].x, v[j].y, v[j].z, v[j].w};
                #pragma unroll
                for (int e = 0; e < 4; ++e)
                    #pragma unroll
                    for (int k = 0; k < NBD; ++k)
                        dot[k] += x[e] * wreg[j][e][k];
            }

            #pragma unroll
            for (int k = 0; k < NBD; ++k)
                #pragma unroll
                for (int off = 32; off; off >>= 1)
                    dot[k] += __shfl_xor(dot[k], off);

            if (lane == 0) {
                float l[NBD] = {dot[0] + b0, dot[1] + b1, dot[2] + b2,
                                dot[3] + b3, dot[4] + b4};
                float m = l[0];
                #pragma unroll
                for (int k = 1; k < NBD; ++k) m = fmaxf(m, l[k]);
                float ssum = 0.f;
                #pragma unroll
                for (int k = 0; k < NBD; ++k) ssum += expf(l[k] - m);
                const float lse = logf(ssum);
                const int   t   = tgt[token];
                nll_sum += -(l[t] - m - lse);
                msk_sum += 1.0f;
            }
        }
    }

    __shared__ float s_n[4], s_m[4];
    if (lane == 0) { s_n[wid] = nll_sum; s_m[wid] = msk_sum; }
    __syncthreads();
    if (threadIdx.x == 0) {
        out_part[blockIdx.x] =
            make_float2(s_n[0] + s_n[1] + s_n[2] + s_n[3],
                        s_m[0] + s_m[1] + s_m[2] + s_m[3]);
    }
}

// ---------------------------------------------------------------------------
// Kernel 2: region loss. One wave per region (4/block), exact-len loop, no
// LDS, no barriers. Measured equal to the LDS form (R11); runs after bd so
// seg==1 rows are L3-warm.
// ---------------------------------------------------------------------------
__global__ __launch_bounds__(256) void region_kernel(
    const float* __restrict__ wr, const float* __restrict__ Wr,
    const float* __restrict__ br, const int* __restrict__ rstart,
    const int* __restrict__ rlen, const int* __restrict__ rbatch,
    const int* __restrict__ rlabel, float* __restrict__ out_nll)
{
    const int wid  = threadIdx.x >> 6;
    const int lane = threadIdx.x & 63;
    const int r    = blockIdx.x * 4 + wid;    // 0..4095

    const int   start = rstart[r];
    const int   len   = rlen[r] + 1;          // 1..16 rows
    const int   b     = rbatch[r];
    const float inv   = 1.0f / (float)len;

    const float4* base =
        (const float4*)wr + ((size_t)b * SS + start) * HH4;

    float4 m0 = {0.f, 0.f, 0.f, 0.f};
    float4 m1 = {0.f, 0.f, 0.f, 0.f};
    float4 m2 = {0.f, 0.f, 0.f, 0.f};

    #pragma unroll 2
    for (int row = 0; row < len; ++row) {
        const float4* p = base + (size_t)row * HH4;
        const float4 u0 = p[lane];
        const float4 u1 = p[lane + 64];
        const float4 u2 = p[lane + 128];
        m0.x += u0.x; m0.y += u0.y; m0.z += u0.z; m0.w += u0.w;
        m1.x += u1.x; m1.y += u1.y; m1.z += u1.z; m1.w += u1.w;
        m2.x += u2.x; m2.y += u2.y; m2.z += u2.z; m2.w += u2.w;
    }

    float part[NC];
    #pragma unroll
    for (int c = 0; c < NC; ++c) part[c] = 0.f;

    const float mv[3][4] = {{m0.x * inv, m0.y * inv, m0.z * inv, m0.w * inv},
                            {m1.x * inv, m1.y * inv, m1.z * inv, m1.w * inv},
                            {m2.x * inv, m2.y * inv, m2.z * inv, m2.w * inv}};
    #pragma unroll
    for (int g = 0; g < 3; ++g) {
        const int f = lane + 64 * g;
        const float4* wv = (const float4*)(Wr + (size_t)4 * f * NC);
        #pragma unroll
        for (int j = 0; j < 9; ++j) {
            const float4 x = wv[j];
            const float vv[4] = {x.x, x.y, x.z, x.w};
            #pragma unroll
            for (int q = 0; q < 4; ++q) {
                const int flat = 4 * j + q;            // 0..35 = e*9+c
                part[flat % NC] += mv[g][flat / NC] * vv[q];
            }
        }
    }

    #pragma unroll
    for (int c = 0; c < NC; ++c)
        #pragma unroll
        for (int off = 32; off; off >>= 1)
            part[c] += __shfl_xor(part[c], off);

    if (lane == 0) {
        float l[NC];
        #pragma unroll
        for (int c = 0; c < NC; ++c) l[c] = part[c] + br[c];
        float mx = l[0];
        #pragma unroll
        for (int c = 1; c < NC; ++c) mx = fmaxf(mx, l[c]);
        float ssum = 0.f;
        #pragma unroll
        for (int c = 0; c < NC; ++c) ssum += expf(l[c] - mx);
        const float lse = logf(ssum);
        const int   t   = rlabel[r];
        out_nll[r] = -(l[t] - mx - lse);
    }
}

// ---------------------------------------------------------------------------
// Kernel 3: final reduction (1 block, 256 threads, f64 accumulation).
// ---------------------------------------------------------------------------
__global__ __launch_bounds__(256) void fin_kernel(
    const float2* __restrict__ bdp, const float* __restrict__ rnll,
    float* __restrict__ out)
{
    const int tid  = threadIdx.x;
    const int wid  = tid >> 6;
    const int lane = tid & 63;

    double a = 0.0, c = 0.0, e = 0.0;
    for (int i = tid; i < NB_BD; i += 256) {
        const float2 p = bdp[i];
        a += (double)p.x;
        c += (double)p.y;
    }
    for (int i = tid; i < NR; i += 256) e += (double)rnll[i];

    #pragma unroll
    for (int off = 32; off; off >>= 1) {
        a += __shfl_xor(a, off);
        c += __shfl_xor(c, off);
        e += __shfl_xor(e, off);
    }

    __shared__ double sa[4], sc[4], se[4];
    if (lane == 0) { sa[wid] = a; sc[wid] = c; se[wid] = e; }
    __syncthreads();

    if (tid == 0) {
        const double A = sa[0] + sa[1] + sa[2] + sa[3];
        const double C = sc[0] + sc[1] + sc[2] + sc[3];
        const double E = se[0] + se[1] + se[2] + se[3];
        const float ent = (float)(E / (double)NR);
        const float bd  = (float)(A / (C + 1e-6));
        out[0] = 0.3f * ent + 0.7f * bd;
    }
}

extern "C" void kernel_launch(void* const* d_in, const int* in_sizes, int n_in,
                              void* d_out, int out_size, void* d_ws, size_t ws_size,
                              hipStream_t stream)
{
    const float* wr     = (const float*)d_in[0];
    const float* Ws     = (const float*)d_in[1];
    const float* bs     = (const float*)d_in[2];
    const float* Wr     = (const float*)d_in[3];
    const float* br     = (const float*)d_in[4];
    const int*   tgt    = (const int*)d_in[5];
    const int*   seg    = (const int*)d_in[6];
    const int*   rstart = (const int*)d_in[7];
    const int*   rlen   = (const int*)d_in[8];
    const int*   rbatch = (const int*)d_in[9];
    const int*   rlabel = (const int*)d_in[10];

    float2* bdp  = (float2*)d_ws;                                   // 16 KB
    float*  rnll = (float*)((char*)d_ws + NB_BD * sizeof(float2));  // 16 KB

    bd_kernel<<<NB_BD, 256, 0, stream>>>(wr, Ws, bs, tgt, seg, bdp);
    region_kernel<<<NR / 4, 256, 0, stream>>>(wr, Wr, br, rstart, rlen,
                                              rbatch, rlabel, rnll);
    fin_kernel<<<1, 256, 0, stream>>>(bdp, rnll, (float*)d_out);
}

// Round 13
// 188.434 us; speedup vs baseline: 1.0326x; 1.0326x over previous
//
#include <hip/hip_runtime.h>

#define BB 64
#define SS 512
#define HH 768
#define HH4 (HH / 4)      // 192 float4 per row
#define NBD 5
#define NC 9
#define NR 4096
#define NB_BD 2048        // boundary blocks (bid%3 != 0)
#define NB_RG 1024        // region blocks (bid%3 == 0), 4 regions each
#define NBLK (NB_BD + NB_RG)   // 3072

// ---------------------------------------------------------------------------
// Fused kernel = R11 structure (measured 60.2us, VGPR 64, FETCH 100MB) with
// ONE mutation: wave-uniform seg-skip in the bd path (readfirstlane + scalar
// branch) -- skips the entire 3KB row read + dot + butterfly + softmax for
// seg==0 tokens (~50%). Region path and 2:1 block interleave unchanged.
// ---------------------------------------------------------------------------
__global__ __launch_bounds__(256) void fused_kernel(
    const float* __restrict__ wr, const float* __restrict__ Ws,
    const float* __restrict__ bs, const int* __restrict__ tgt,
    const int* __restrict__ seg,
    const float* __restrict__ Wr, const float* __restrict__ br,
    const int* __restrict__ rstart, const int* __restrict__ rlen,
    const int* __restrict__ rbatch, const int* __restrict__ rlabel,
    float2* __restrict__ bd_part, float* __restrict__ rnll)
{
    const int tid  = threadIdx.x;
    const int wid  = tid >> 6;
    const int lane = tid & 63;
    const int bid  = blockIdx.x;

    if (bid % 3 != 0) {
        // ================= boundary path (R11 + seg-skip) ================
        const int bb = bid - bid / 3 - 1;   // 0..2047
        const int gw = bb * 4 + wid;        // 0..8191

        float wreg[3][4][NBD];
        #pragma unroll
        for (int j = 0; j < 3; ++j) {
            const float4* wp = (const float4*)(Ws + (4 * lane + 256 * j) * NBD);
            #pragma unroll
            for (int p = 0; p < 5; ++p) {
                const float4 f = wp[p];
                const float vv[4] = {f.x, f.y, f.z, f.w};
                #pragma unroll
                for (int q = 0; q < 4; ++q) {
                    const int flat = 4 * p + q;            // 0..19
                    wreg[j][flat / NBD][flat % NBD] = vv[q];
                }
            }
        }
        const float b0 = bs[0], b1 = bs[1], b2 = bs[2], b3 = bs[3], b4 = bs[4];

        float nll_sum = 0.f, msk_sum = 0.f;

        #pragma unroll
        for (int i = 0; i < 4; ++i) {
            const int token = gw + 8192 * i;
            // wave-uniform mask -> scalar branch skips load+compute entirely
            const int m_u = __builtin_amdgcn_readfirstlane(seg[token]);
            if (m_u != 0) {
                const float4* row4 = (const float4*)(wr + (size_t)token * HH);

                float4 v[3];
                #pragma unroll
                for (int j = 0; j < 3; ++j) v[j] = row4[lane + 64 * j];

                float dot[NBD] = {0.f, 0.f, 0.f, 0.f, 0.f};
                #pragma unroll
                for (int j = 0; j < 3; ++j) {
                    const float x[4] = {v[j].x, v[j].y, v[j].z, v[j].w};
                    #pragma unroll
                    for (int e = 0; e < 4; ++e)
                        #pragma unroll
                        for (int k = 0; k < NBD; ++k)
                            dot[k] += x[e] * wreg[j][e][k];
                }

                #pragma unroll
                for (int k = 0; k < NBD; ++k)
                    #pragma unroll
                    for (int off = 32; off; off >>= 1)
                        dot[k] += __shfl_xor(dot[k], off);

                if (lane == 0) {
                    float l[NBD] = {dot[0] + b0, dot[1] + b1, dot[2] + b2,
                                    dot[3] + b3, dot[4] + b4};
                    float m = l[0];
                    #pragma unroll
                    for (int k = 1; k < NBD; ++k) m = fmaxf(m, l[k]);
                    float ssum = 0.f;
                    #pragma unroll
                    for (int k = 0; k < NBD; ++k) ssum += expf(l[k] - m);
                    const float lse = logf(ssum);
                    const int   t   = tgt[token];
                    nll_sum += -(l[t] - m - lse);
                    msk_sum += 1.0f;
                }
            }
        }

        __shared__ float s_n[4], s_m[4];
        if (lane == 0) { s_n[wid] = nll_sum; s_m[wid] = msk_sum; }
        __syncthreads();
        if (tid == 0) {
            bd_part[bb] = make_float2(s_n[0] + s_n[1] + s_n[2] + s_n[3],
                                      s_m[0] + s_m[1] + s_m[2] + s_m[3]);
        }
    } else {
        // ============ region path: one wave per region, exact len ========
        const int r = (bid / 3) * 4 + wid;   // 0..4095

        const int   start = rstart[r];
        const int   len   = rlen[r] + 1;     // 1..16 rows
        const int   b     = rbatch[r];
        const float inv   = 1.0f / (float)len;

        const float4* base =
            (const float4*)wr + ((size_t)b * SS + start) * HH4;

        float4 m0 = {0.f, 0.f, 0.f, 0.f};
        float4 m1 = {0.f, 0.f, 0.f, 0.f};
        float4 m2 = {0.f, 0.f, 0.f, 0.f};

        #pragma unroll 2
        for (int row = 0; row < len; ++row) {
            const float4* p = base + (size_t)row * HH4;
            const float4 u0 = p[lane];
            const float4 u1 = p[lane + 64];
            const float4 u2 = p[lane + 128];
            m0.x += u0.x; m0.y += u0.y; m0.z += u0.z; m0.w += u0.w;
            m1.x += u1.x; m1.y += u1.y; m1.z += u1.z; m1.w += u1.w;
            m2.x += u2.x; m2.y += u2.y; m2.z += u2.z; m2.w += u2.w;
        }

        float part[NC];
        #pragma unroll
        for (int c = 0; c < NC; ++c) part[c] = 0.f;

        const float mv[3][4] = {{m0.x * inv, m0.y * inv, m0.z * inv, m0.w * inv},
                                {m1.x * inv, m1.y * inv, m1.z * inv, m1.w * inv},
                                {m2.x * inv, m2.y * inv, m2.z * inv, m2.w * inv}};
        #pragma unroll
        for (int g = 0; g < 3; ++g) {
            const int f = lane + 64 * g;
            const float4* wv = (const float4*)(Wr + (size_t)4 * f * NC);
            #pragma unroll
            for (int j = 0; j < 9; ++j) {
                const float4 x = wv[j];
                const float vv[4] = {x.x, x.y, x.z, x.w};
                #pragma unroll
                for (int q = 0; q < 4; ++q) {
                    const int flat = 4 * j + q;            // 0..35 = e*9+c
                    part[flat % NC] += mv[g][flat / NC] * vv[q];
                }
            }
        }

        #pragma unroll
        for (int c = 0; c < NC; ++c)
            #pragma unroll
            for (int off = 32; off; off >>= 1)
                part[c] += __shfl_xor(part[c], off);

        if (lane == 0) {
            float l[NC];
            #pragma unroll
            for (int c = 0; c < NC; ++c) l[c] = part[c] + br[c];
            float mx = l[0];
            #pragma unroll
            for (int c = 1; c < NC; ++c) mx = fmaxf(mx, l[c]);
            float ssum = 0.f;
            #pragma unroll
            for (int c = 0; c < NC; ++c) ssum += expf(l[c] - mx);
            const float lse = logf(ssum);
            const int   t   = rlabel[r];
            rnll[r] = -(l[t] - mx - lse);
        }
    }
}

// ---------------------------------------------------------------------------
// Final reduction (1 block, 256 threads, f64 accumulation). ~4us measured.
// ---------------------------------------------------------------------------
__global__ __launch_bounds__(256) void fin_kernel(
    const float2* __restrict__ bdp, const float* __restrict__ rnll,
    float* __restrict__ out)
{
    const int tid  = threadIdx.x;
    const int wid  = tid >> 6;
    const int lane = tid & 63;

    double a = 0.0, c = 0.0, e = 0.0;
    for (int i = tid; i < NB_BD; i += 256) {
        const float2 p = bdp[i];
        a += (double)p.x;
        c += (double)p.y;
    }
    for (int i = tid; i < NR; i += 256) e += (double)rnll[i];

    #pragma unroll
    for (int off = 32; off; off >>= 1) {
        a += __shfl_xor(a, off);
        c += __shfl_xor(c, off);
        e += __shfl_xor(e, off);
    }

    __shared__ double sa[4], sc[4], se[4];
    if (lane == 0) { sa[wid] = a; sc[wid] = c; se[wid] = e; }
    __syncthreads();

    if (tid == 0) {
        const double A = sa[0] + sa[1] + sa[2] + sa[3];
        const double C = sc[0] + sc[1] + sc[2] + sc[3];
        const double E = se[0] + se[1] + se[2] + se[3];
        const float ent = (float)(E / (double)NR);
        const float bd  = (float)(A / (C + 1e-6));
        out[0] = 0.3f * ent + 0.7f * bd;
    }
}

extern "C" void kernel_launch(void* const* d_in, const int* in_sizes, int n_in,
                              void* d_out, int out_size, void* d_ws, size_t ws_size,
                              hipStream_t stream)
{
    const float* wr     = (const float*)d_in[0];
    const float* Ws     = (const float*)d_in[1];
    const float* bs     = (const float*)d_in[2];
    const float* Wr     = (const float*)d_in[3];
    const float* br     = (const float*)d_in[4];
    const int*   tgt    = (const int*)d_in[5];
    const int*   seg    = (const int*)d_in[6];
    const int*   rstart = (const int*)d_in[7];
    const int*   rlen   = (const int*)d_in[8];
    const int*   rbatch = (const int*)d_in[9];
    const int*   rlabel = (const int*)d_in[10];

    float2* bdp  = (float2*)d_ws;                                   // 16 KB
    float*  rnll = (float*)((char*)d_ws + NB_BD * sizeof(float2));  // 16 KB

    fused_kernel<<<NBLK, 256, 0, stream>>>(wr, Ws, bs, tgt, seg,
                                           Wr, br, rstart, rlen, rbatch, rlabel,
                                           bdp, rnll);
    fin_kernel<<<1, 256, 0, stream>>>(bdp, rnll, (float*)d_out);
}

// Round 14
// 187.148 us; speedup vs baseline: 1.0397x; 1.0069x over previous
//
#include <hip/hip_runtime.h>

#define SS 512
#define HH 768
#define HH4 192           // float4 per row
#define NBD 5
#define NC 9
#define NR 4096
#define NB_RG 1024        // region blocks: bid 0..1023, one region per wave
#define NB_BD 512         // bd blocks: bid 1024..1535, 64 tokens/block (4 lanes/token)
#define NBLK (NB_RG + NB_BD)
#define WS_LDS_SZ (HH * NBD + 24)   // 3840 floats + 8-float pad per 960

// ---------------------------------------------------------------------------
// Fused kernel, role by bid range (region first: latency-bound long poles
// start early; bd blocks stream HBM alongside).
//
// bd path (per-lane-token): lane group of 4 owns one token; each lane streams
// its 768B quarter-row as 48 INDEPENDENT float4 loads (deep MLP, no cross-
// lane dependency until 2 shfl_xor at the end). Ws staged in LDS, padded so
// the 4 q-groups (stride 960 floats = bank 0 alias) land on distinct banks.
// Per-lane seg predication: EXEC-masked lanes issue no loads (~50% traffic).
//
// region path: R12 per-wave exact-len form, unroll 4 (12 loads in flight).
// ---------------------------------------------------------------------------
__global__ __launch_bounds__(256) void fused_kernel(
    const float* __restrict__ wr, const float* __restrict__ Ws,
    const float* __restrict__ bs, const int* __restrict__ tgt,
    const int* __restrict__ seg,
    const float* __restrict__ Wr, const float* __restrict__ br,
    const int* __restrict__ rstart, const int* __restrict__ rlen,
    const int* __restrict__ rbatch, const int* __restrict__ rlabel,
    float2* __restrict__ bd_part, float* __restrict__ rnll)
{
    const int tid  = threadIdx.x;
    const int wid  = tid >> 6;
    const int lane = tid & 63;
    const int bid  = blockIdx.x;

    __shared__ float ws_lds[WS_LDS_SZ];
    __shared__ float s_n[4], s_m[4];

    if (bid < NB_RG) {
        // ============ region path: one wave per region, exact len ========
        const int r = bid * 4 + wid;         // 0..4095

        const int   start = rstart[r];
        const int   len   = rlen[r] + 1;     // 1..16 rows
        const int   b     = rbatch[r];
        const float inv   = 1.0f / (float)len;

        const float4* base =
            (const float4*)wr + ((size_t)b * SS + start) * HH4;

        float4 m0 = {0.f, 0.f, 0.f, 0.f};
        float4 m1 = {0.f, 0.f, 0.f, 0.f};
        float4 m2 = {0.f, 0.f, 0.f, 0.f};

        #pragma unroll 4
        for (int row = 0; row < len; ++row) {
            const float4* p = base + (size_t)row * HH4;
            const float4 u0 = p[lane];
            const float4 u1 = p[lane + 64];
            const float4 u2 = p[lane + 128];
            m0.x += u0.x; m0.y += u0.y; m0.z += u0.z; m0.w += u0.w;
            m1.x += u1.x; m1.y += u1.y; m1.z += u1.z; m1.w += u1.w;
            m2.x += u2.x; m2.y += u2.y; m2.z += u2.z; m2.w += u2.w;
        }

        float part[NC];
        #pragma unroll
        for (int c = 0; c < NC; ++c) part[c] = 0.f;

        const float mv[3][4] = {{m0.x * inv, m0.y * inv, m0.z * inv, m0.w * inv},
                                {m1.x * inv, m1.y * inv, m1.z * inv, m1.w * inv},
                                {m2.x * inv, m2.y * inv, m2.z * inv, m2.w * inv}};
        #pragma unroll
        for (int g = 0; g < 3; ++g) {
            const int f = lane + 64 * g;
            const float4* wv = (const float4*)(Wr + (size_t)4 * f * NC);
            #pragma unroll
            for (int j = 0; j < 9; ++j) {
                const float4 x = wv[j];
                const float vv[4] = {x.x, x.y, x.z, x.w};
                #pragma unroll
                for (int qq = 0; qq < 4; ++qq) {
                    const int flat = 4 * j + qq;           // 0..35 = e*9+c
                    part[flat % NC] += mv[g][flat / NC] * vv[qq];
                }
            }
        }

        #pragma unroll
        for (int c = 0; c < NC; ++c)
            #pragma unroll
            for (int off = 32; off; off >>= 1)
                part[c] += __shfl_xor(part[c], off);

        if (lane == 0) {
            float l[NC];
            #pragma unroll
            for (int c = 0; c < NC; ++c) l[c] = part[c] + br[c];
            float mx = l[0];
            #pragma unroll
            for (int c = 1; c < NC; ++c) mx = fmaxf(mx, l[c]);
            float ssum = 0.f;
            #pragma unroll
            for (int c = 0; c < NC; ++c) ssum += expf(l[c] - mx);
            const float lse = logf(ssum);
            const int   t   = rlabel[r];
            rnll[r] = -(l[t] - mx - lse);
        }
    } else {
        // ================= bd path: 4 lanes per token ====================
        const int bb = bid - NB_RG;          // 0..511

        // stage Ws into LDS with +8-float pad per 960 (q-groups alias bank 0
        // at stride 960 = 30*32; pad makes q-offset 968 = bank 8q, distinct)
        for (int i = tid; i < HH * NBD; i += 256)
            ws_lds[i + (i / 960) * 8] = Ws[i];
        __syncthreads();

        const int gl    = bb * 256 + tid;    // global lane, 0..131071
        const int token = gl >> 2;           // 0..32767
        const int q     = gl & 3;            // h-quarter
        const int seg_t = seg[token];

        float dot[NBD] = {0.f, 0.f, 0.f, 0.f, 0.f};

        if (seg_t != 0) {                    // per-lane predication: masked
            const float4* row4 =             // lanes issue NO loads
                (const float4*)(wr + (size_t)token * HH) + q * 48;
            const float* wsb = ws_lds + 968 * q;   // padded base for quarter
            #pragma unroll 4
            for (int jj = 0; jj < 48; ++jj) {
                const float4 v = row4[jj];
                const float* wp = wsb + 20 * jj;   // 4 h-rows x 5 classes
                const float x[4] = {v.x, v.y, v.z, v.w};
                #pragma unroll
                for (int e = 0; e < 4; ++e)
                    #pragma unroll
                    for (int k = 0; k < NBD; ++k)
                        dot[k] += x[e] * wp[e * NBD + k];
            }
        }

        // combine the 4 lanes of the token group
        #pragma unroll
        for (int k = 0; k < NBD; ++k) {
            dot[k] += __shfl_xor(dot[k], 1);
            dot[k] += __shfl_xor(dot[k], 2);
        }

        float nll = 0.f, msk = 0.f;
        if (q == 0 && seg_t != 0) {
            float l[NBD];
            #pragma unroll
            for (int k = 0; k < NBD; ++k) l[k] = dot[k] + bs[k];
            float m = l[0];
            #pragma unroll
            for (int k = 1; k < NBD; ++k) m = fmaxf(m, l[k]);
            float ssum = 0.f;
            #pragma unroll
            for (int k = 0; k < NBD; ++k) ssum += expf(l[k] - m);
            const float lse = logf(ssum);
            const int   t   = tgt[token];
            nll = -(l[t] - m - lse);
            msk = 1.0f;
        }

        // wave-wide sum (nll/msk nonzero only on q==0&seg lanes)
        #pragma unroll
        for (int off = 32; off; off >>= 1) {
            nll += __shfl_xor(nll, off);
            msk += __shfl_xor(msk, off);
        }

        if (lane == 0) { s_n[wid] = nll; s_m[wid] = msk; }
        __syncthreads();
        if (tid == 0) {
            bd_part[bb] = make_float2(s_n[0] + s_n[1] + s_n[2] + s_n[3],
                                      s_m[0] + s_m[1] + s_m[2] + s_m[3]);
        }
    }
}

// ---------------------------------------------------------------------------
// Final reduction (1 block, 256 threads, f64 accumulation). ~4us measured.
// ---------------------------------------------------------------------------
__global__ __launch_bounds__(256) void fin_kernel(
    const float2* __restrict__ bdp, const float* __restrict__ rnll,
    float* __restrict__ out)
{
    const int tid  = threadIdx.x;
    const int wid  = tid >> 6;
    const int lane = tid & 63;

    double a = 0.0, c = 0.0, e = 0.0;
    for (int i = tid; i < NB_BD; i += 256) {
        const float2 p = bdp[i];
        a += (double)p.x;
        c += (double)p.y;
    }
    for (int i = tid; i < NR; i += 256) e += (double)rnll[i];

    #pragma unroll
    for (int off = 32; off; off >>= 1) {
        a += __shfl_xor(a, off);
        c += __shfl_xor(c, off);
        e += __shfl_xor(e, off);
    }

    __shared__ double sa[4], sc[4], se[4];
    if (lane == 0) { sa[wid] = a; sc[wid] = c; se[wid] = e; }
    __syncthreads();

    if (tid == 0) {
        const double A = sa[0] + sa[1] + sa[2] + sa[3];
        const double C = sc[0] + sc[1] + sc[2] + sc[3];
        const double E = se[0] + se[1] + se[2] + se[3];
        const float ent = (float)(E / (double)NR);
        const float bd  = (float)(A / (C + 1e-6));
        out[0] = 0.3f * ent + 0.7f * bd;
    }
}

extern "C" void kernel_launch(void* const* d_in, const int* in_sizes, int n_in,
                              void* d_out, int out_size, void* d_ws, size_t ws_size,
                              hipStream_t stream)
{
    const float* wr     = (const float*)d_in[0];
    const float* Ws     = (const float*)d_in[1];
    const float* bs     = (const float*)d_in[2];
    const float* Wr     = (const float*)d_in[3];
    const float* br     = (const float*)d_in[4];
    const int*   tgt    = (const int*)d_in[5];
    const int*   seg    = (const int*)d_in[6];
    const int*   rstart = (const int*)d_in[7];
    const int*   rlen   = (const int*)d_in[8];
    const int*   rbatch = (const int*)d_in[9];
    const int*   rlabel = (const int*)d_in[10];

    float2* bdp  = (float2*)d_ws;                                   // 4 KB
    float*  rnll = (float*)((char*)d_ws + NB_BD * sizeof(float2));  // 16 KB

    fused_kernel<<<NBLK, 256, 0, stream>>>(wr, Ws, bs, tgt, seg,
                                           Wr, br, rstart, rlen, rbatch, rlabel,
                                           bdp, rnll);
    fin_kernel<<<1, 256, 0, stream>>>(bdp, rnll, (float*)d_out);
}